// Round 1
// baseline (462.520 us; speedup 1.0000x reference)
//
#include <hip/hip_runtime.h>
#include <hip/hip_bf16.h>

// t-product: C[b,i,n,:] = sum_j A[b,i,j,:] (*) B[b,j,n,:]  (circular conv, len 64)
// Implemented as: rFFT(64->33 freqs) -> 264 complex GEMMs (as one real bf16 MFMA
// GEMM per (b,k) plane via the [Ar|Ai] @ [[Br,Bi],[-Bi,Br]] embedding) -> irFFT.
//
// Workspace layout (bf16):
//   Af  [264][256][512] : per (b,k) plane, row i, cols [Ar(j) | Ai(j)]      69.2 MB
//   Bt  [264][512][512] : per (b,k) plane, row n2, cols j2 (B-embedding^T) 138.4 MB
//   Cf  [264][256][512] : per (b,k) plane, row i, cols [Cr(n) | Ci(n)]      69.2 MB

typedef __bf16 bf16x8 __attribute__((ext_vector_type(8)));
typedef float f32x4 __attribute__((ext_vector_type(4)));

// ---------------- twiddles: cos/sin(pi*k/32), k=0..31 (constant-folded) ---------
constexpr float TWC[32] = {
  1.0f, 0.99518472667f, 0.98078528040f, 0.95694033573f,
  0.92387953251f, 0.88192126435f, 0.83146961230f, 0.77301045336f,
  0.70710678119f, 0.63439328416f, 0.55557023302f, 0.47139673683f,
  0.38268343236f, 0.29028467725f, 0.19509032202f, 0.09801714033f,
  0.0f, -0.09801714033f, -0.19509032202f, -0.29028467725f,
  -0.38268343236f, -0.47139673683f, -0.55557023302f, -0.63439328416f,
  -0.70710678119f, -0.77301045336f, -0.83146961230f, -0.88192126435f,
  -0.92387953251f, -0.95694033573f, -0.98078528040f, -0.99518472667f
};
constexpr float TWS[32] = {
  0.0f, 0.09801714033f, 0.19509032202f, 0.29028467725f,
  0.38268343236f, 0.47139673683f, 0.55557023302f, 0.63439328416f,
  0.70710678119f, 0.77301045336f, 0.83146961230f, 0.88192126435f,
  0.92387953251f, 0.95694033573f, 0.98078528040f, 0.99518472667f,
  1.0f, 0.99518472667f, 0.98078528040f, 0.95694033573f,
  0.92387953251f, 0.88192126435f, 0.83146961230f, 0.77301045336f,
  0.70710678119f, 0.63439328416f, 0.55557023302f, 0.47139673683f,
  0.38268343236f, 0.29028467725f, 0.19509032202f, 0.09801714033f
};

__device__ __forceinline__ constexpr int rev6(int x) {
  int r = 0;
  for (int b = 0; b < 6; ++b) r = (r << 1) | ((x >> b) & 1);
  return r;
}

// In-register radix-2 DIT FFT, length 64. SIGN=-1: forward (e^{-2pi i kt/64}),
// SIGN=+1: inverse kernel sum (no 1/64 scale).
template <int SIGN>
__device__ __forceinline__ void fft64(float* re, float* im) {
#pragma unroll
  for (int i = 0; i < 64; ++i) {
    const int j = rev6(i);
    if (j > i) {
      float tr = re[i]; re[i] = re[j]; re[j] = tr;
      float ti = im[i]; im[i] = im[j]; im[j] = ti;
    }
  }
#pragma unroll
  for (int s = 0; s < 6; ++s) {
    const int half = 1 << s;
    const int m = 2 << s;
    const int tstep = 64 >> (s + 1);
#pragma unroll
    for (int kb = 0; kb < 64; kb += m) {
#pragma unroll
      for (int t = 0; t < half; ++t) {
        const int idx = t * tstep;                 // 0..31
        const float wr = TWC[idx];
        const float wi = SIGN * TWS[idx];         // fwd: -sin, inv: +sin
        const int a = kb + t, b = a + half;
        const float xr = re[b] * wr - im[b] * wi;
        const float xi = re[b] * wi + im[b] * wr;
        re[b] = re[a] - xr; im[b] = im[a] - xi;
        re[a] += xr;        im[a] += xi;
      }
    }
  }
}

// ---------------- kernel 1: FFT of A -> Af planes --------------------------------
// block = 64 threads, blockIdx.x = (b*256+i)*4 + jblk ; thread handles tube j.
__global__ __launch_bounds__(64) void fft_a_kernel(const float* __restrict__ A,
                                                   __bf16* __restrict__ Af) {
  const int blk = blockIdx.x;
  const int jblk = blk & 3;
  const int bi = blk >> 2;                  // b*256 + i
  const int lane = threadIdx.x;
  __shared__ float lds[64 * 65];
  const float* src = A + (((size_t)bi * 256) + (size_t)jblk * 64) * 64;
#pragma unroll
  for (int r = 0; r < 64; ++r) lds[r * 65 + lane] = src[(size_t)r * 64 + lane];
  __syncthreads();
  float re[64], im[64];
#pragma unroll
  for (int e = 0; e < 64; ++e) { re[e] = lds[lane * 65 + e]; im[e] = 0.0f; }
  fft64<-1>(re, im);
  const int b = bi >> 8, i = bi & 255;
  const int j = jblk * 64 + lane;
#pragma unroll
  for (int k = 0; k <= 32; ++k) {
    const size_t plane = (size_t)(b * 33 + k) * (256 * 512);
    Af[plane + (size_t)i * 512 + j]       = (__bf16)re[k];
    Af[plane + (size_t)i * 512 + 256 + j] = (__bf16)im[k];
  }
}

// ---------------- kernel 2: FFT of B -> Bt (embedded, transposed) ---------------
// Bt[n2][j2]: [n][j]=Br, [n][256+j]=-Bi, [256+n][j]=Bi, [256+n][256+j]=Br
__global__ __launch_bounds__(64) void fft_b_kernel(const float* __restrict__ B,
                                                   __bf16* __restrict__ Bt) {
  const int blk = blockIdx.x;
  const int jblk = blk & 3;
  const int bn = blk >> 2;                  // b*256 + n
  const int b = bn >> 8, n = bn & 255;
  const int lane = threadIdx.x;
  __shared__ float lds[64 * 65];
#pragma unroll
  for (int r = 0; r < 64; ++r) {
    const size_t base = (((size_t)b * 256 + (size_t)(jblk * 64 + r)) * 256 + n) * 64;
    lds[r * 65 + lane] = B[base + lane];
  }
  __syncthreads();
  float re[64], im[64];
#pragma unroll
  for (int e = 0; e < 64; ++e) { re[e] = lds[lane * 65 + e]; im[e] = 0.0f; }
  fft64<-1>(re, im);
  const int j = jblk * 64 + lane;
#pragma unroll
  for (int k = 0; k <= 32; ++k) {
    const size_t plane = (size_t)(b * 33 + k) * (512 * 512);
    const float br = re[k], bi = im[k];
    Bt[plane + (size_t)n * 512 + j]               = (__bf16)br;
    Bt[plane + (size_t)n * 512 + 256 + j]         = (__bf16)(-bi);
    Bt[plane + (size_t)(256 + n) * 512 + j]       = (__bf16)bi;
    Bt[plane + (size_t)(256 + n) * 512 + 256 + j] = (__bf16)br;
  }
}

// ---------------- kernel 3: batched bf16 MFMA GEMM ------------------------------
// Per plane g (264): C[256][512] = Afull[256][512] * BtFull[512][512]^T
// (both operands stored row x K). 128x128 tile, BK=64, 4 waves of 64x64.
__device__ __forceinline__ void gload_lds16(const void* g, void* l) {
  __builtin_amdgcn_global_load_lds(
      (const __attribute__((address_space(1))) void*)g,
      (__attribute__((address_space(3))) void*)l, 16, 0, 0);
}

__global__ __launch_bounds__(256) void gemm_kernel(const __bf16* __restrict__ Af,
                                                   const __bf16* __restrict__ Bt,
                                                   __bf16* __restrict__ Cf) {
  const int g = blockIdx.z;
  const int n0 = blockIdx.x * 128;          // 0..384
  const int i0 = blockIdx.y * 128;          // 0,128
  const int tid = threadIdx.x;
  const int lane = tid & 63, wv = tid >> 6;
  const int wm = wv >> 1, wn = wv & 1;
  const int lm = lane & 15, q = lane >> 4;

  __shared__ __bf16 As[128 * 64];
  __shared__ __bf16 Bs[128 * 64];

  const __bf16* aPlane = Af + (size_t)g * (256 * 512);
  const __bf16* bPlane = Bt + (size_t)g * (512 * 512);

  f32x4 acc[4][4];
#pragma unroll
  for (int mi = 0; mi < 4; ++mi)
#pragma unroll
    for (int ni = 0; ni < 4; ++ni) acc[mi][ni] = f32x4{0.f, 0.f, 0.f, 0.f};

  for (int kt = 0; kt < 8; ++kt) {
    // stage: 16KB per tile = 16 chunks of 1024B; wave wv stages chunk p*4+wv
#pragma unroll
    for (int p = 0; p < 4; ++p) {
      const int row = p * 32 + wv * 8 + (lane >> 3);
      const int ke = (lane & 7) * 8;        // bf16 elements within BK=64
      const __bf16* ga = aPlane + (size_t)(i0 + row) * 512 + kt * 64 + ke;
      const __bf16* gb = bPlane + (size_t)(n0 + row) * 512 + kt * 64 + ke;
      gload_lds16(ga, (char*)As + p * 4096 + wv * 1024);
      gload_lds16(gb, (char*)Bs + p * 4096 + wv * 1024);
    }
    __syncthreads();
#pragma unroll
    for (int ks = 0; ks < 2; ++ks) {
      bf16x8 af[4], bf[4];
#pragma unroll
      for (int mi = 0; mi < 4; ++mi)
        af[mi] = *(const bf16x8*)&As[(wm * 64 + mi * 16 + lm) * 64 + ks * 32 + q * 8];
#pragma unroll
      for (int ni = 0; ni < 4; ++ni)
        bf[ni] = *(const bf16x8*)&Bs[(wn * 64 + ni * 16 + lm) * 64 + ks * 32 + q * 8];
#pragma unroll
      for (int mi = 0; mi < 4; ++mi)
#pragma unroll
        for (int ni = 0; ni < 4; ++ni)
          acc[mi][ni] = __builtin_amdgcn_mfma_f32_16x16x32_bf16(af[mi], bf[ni],
                                                                acc[mi][ni], 0, 0, 0);
    }
    __syncthreads();
  }

  // epilogue: C/D layout col = lane&15, row = (lane>>4)*4 + reg  [m89/m91]
  __bf16* cPlane = Cf + (size_t)g * (256 * 512);
#pragma unroll
  for (int mi = 0; mi < 4; ++mi) {
#pragma unroll
    for (int ni = 0; ni < 4; ++ni) {
      const int col = n0 + wn * 64 + ni * 16 + lm;
#pragma unroll
      for (int r = 0; r < 4; ++r) {
        const int row = i0 + wm * 64 + mi * 16 + q * 4 + r;
        cPlane[(size_t)row * 512 + col] = (__bf16)acc[mi][ni][r];
      }
    }
  }
}

// ---------------- kernel 4: inverse FFT -> real C -------------------------------
__global__ __launch_bounds__(64) void ifft_kernel(const __bf16* __restrict__ Cf,
                                                  float* __restrict__ C) {
  const int blk = blockIdx.x;
  const int nblk = blk & 3;
  const int bi = blk >> 2;                  // b*256 + i
  const int b = bi >> 8, i = bi & 255;
  const int lane = threadIdx.x;
  const int n = nblk * 64 + lane;
  float re[64], im[64];
#pragma unroll
  for (int k = 0; k <= 32; ++k) {
    const size_t plane = (size_t)(b * 33 + k) * (256 * 512);
    const float cr = (float)Cf[plane + (size_t)i * 512 + n];
    const float ci = (float)Cf[plane + (size_t)i * 512 + 256 + n];
    re[k] = cr; im[k] = ci;
    if (k >= 1 && k <= 31) { re[64 - k] = cr; im[64 - k] = -ci; }
  }
  fft64<1>(re, im);
  __shared__ float lds[64 * 65];
#pragma unroll
  for (int t = 0; t < 64; ++t) lds[lane * 65 + t] = re[t] * (1.0f / 64.0f);
  __syncthreads();
  const size_t base = (((size_t)b * 256 + i) * 256 + (size_t)nblk * 64) * 64;
#pragma unroll
  for (int r = 0; r < 64; ++r) C[base + (size_t)r * 64 + lane] = lds[r * 65 + lane];
}

// ---------------- launcher -------------------------------------------------------
extern "C" void kernel_launch(void* const* d_in, const int* in_sizes, int n_in,
                              void* d_out, int out_size, void* d_ws, size_t ws_size,
                              hipStream_t stream) {
  const float* A = (const float*)d_in[0];
  const float* B = (const float*)d_in[1];
  float* C = (float*)d_out;

  char* ws = (char*)d_ws;
  const size_t afBytes = (size_t)264 * 256 * 512 * 2;   //  69.2 MB
  const size_t btBytes = (size_t)264 * 512 * 512 * 2;   // 138.4 MB
  __bf16* Af = (__bf16*)ws;
  __bf16* Bt = (__bf16*)(ws + afBytes);
  __bf16* Cf = (__bf16*)(ws + afBytes + btBytes);

  fft_a_kernel<<<8192, 64, 0, stream>>>(A, Af);
  fft_b_kernel<<<8192, 64, 0, stream>>>(B, Bt);
  dim3 ggrid(4, 2, 264);
  gemm_kernel<<<ggrid, 256, 0, stream>>>(Af, Bt, Cf);
  ifft_kernel<<<8192, 64, 0, stream>>>(Cf, C);
}

// Round 2
// 418.988 us; speedup vs baseline: 1.1039x; 1.1039x over previous
//
#include <hip/hip_runtime.h>
#include <hip/hip_bf16.h>
#include <stdint.h>

// t-product: C[b,i,n,:] = sum_j A[b,i,j,:] (*) B[b,j,n,:]  (circular conv, len 64)
// rFFT(64->33) -> 264 compact complex GEMMs (4 bf16 MFMAs / tile-pair, 2 accums)
// -> irFFT.
//
// Workspace (bf16), plane = (b*33+k), plane size 256*512 elems for all three:
//   Af [264][256][512] : row i, cols [Ar(j=0..255) | Ai(j)]   69.2 MB
//   Bn [264][256][512] : row n, cols [Br(j) | Bi(j)]          69.2 MB (B^T compact)
//   Cf [264][256][512] : row i, cols [Cr(n) | Ci(n)]          69.2 MB

typedef __bf16 bf16x8 __attribute__((ext_vector_type(8)));
typedef float f32x4 __attribute__((ext_vector_type(4)));

constexpr float TWC[32] = {
  1.0f, 0.99518472667f, 0.98078528040f, 0.95694033573f,
  0.92387953251f, 0.88192126435f, 0.83146961230f, 0.77301045336f,
  0.70710678119f, 0.63439328416f, 0.55557023302f, 0.47139673683f,
  0.38268343236f, 0.29028467725f, 0.19509032202f, 0.09801714033f,
  0.0f, -0.09801714033f, -0.19509032202f, -0.29028467725f,
  -0.38268343236f, -0.47139673683f, -0.55557023302f, -0.63439328416f,
  -0.70710678119f, -0.77301045336f, -0.83146961230f, -0.88192126435f,
  -0.92387953251f, -0.95694033573f, -0.98078528040f, -0.99518472667f
};
constexpr float TWS[32] = {
  0.0f, 0.09801714033f, 0.19509032202f, 0.29028467725f,
  0.38268343236f, 0.47139673683f, 0.55557023302f, 0.63439328416f,
  0.70710678119f, 0.77301045336f, 0.83146961230f, 0.88192126435f,
  0.92387953251f, 0.95694033573f, 0.98078528040f, 0.99518472667f,
  1.0f, 0.99518472667f, 0.98078528040f, 0.95694033573f,
  0.92387953251f, 0.88192126435f, 0.83146961230f, 0.77301045336f,
  0.70710678119f, 0.63439328416f, 0.55557023302f, 0.47139673683f,
  0.38268343236f, 0.29028467725f, 0.19509032202f, 0.09801714033f
};

__device__ __forceinline__ constexpr int rev6(int x) {
  int r = 0;
  for (int b = 0; b < 6; ++b) r = (r << 1) | ((x >> b) & 1);
  return r;
}

template <int SIGN>
__device__ __forceinline__ void fft64(float* re, float* im) {
#pragma unroll
  for (int i = 0; i < 64; ++i) {
    const int j = rev6(i);
    if (j > i) {
      float tr = re[i]; re[i] = re[j]; re[j] = tr;
      float ti = im[i]; im[i] = im[j]; im[j] = ti;
    }
  }
#pragma unroll
  for (int s = 0; s < 6; ++s) {
    const int half = 1 << s;
    const int m = 2 << s;
    const int tstep = 64 >> (s + 1);
#pragma unroll
    for (int kb = 0; kb < 64; kb += m) {
#pragma unroll
      for (int t = 0; t < half; ++t) {
        const int idx = t * tstep;
        const float wr = TWC[idx];
        const float wi = SIGN * TWS[idx];
        const int a = kb + t, b = a + half;
        const float xr = re[b] * wr - im[b] * wi;
        const float xi = re[b] * wi + im[b] * wr;
        re[b] = re[a] - xr; im[b] = im[a] - xi;
        re[a] += xr;        im[a] += xi;
      }
    }
  }
}

// ---------------- kernel 1: FFT of A -> Af --------------------------------------
__global__ __launch_bounds__(64) void fft_a_kernel(const float* __restrict__ A,
                                                   __bf16* __restrict__ Af) {
  const int blk = blockIdx.x;
  const int jblk = blk & 3;
  const int bi = blk >> 2;                  // b*256 + i
  const int l = threadIdx.x;
  const int lm16 = l & 15, lq4 = l >> 4;
  __shared__ float lds[64 * 68];            // [j-row][tube elem], stride 68 (16B-aligned float4)
  const float* src = A + (((size_t)bi * 256) + (size_t)jblk * 64) * 64;
#pragma unroll
  for (int it = 0; it < 16; ++it) {
    const int r = it * 4 + lq4;
    const float4 v = *(const float4*)&src[(size_t)r * 64 + lm16 * 4];
    *(float4*)&lds[r * 68 + lm16 * 4] = v;
  }
  __syncthreads();
  float re[64], im[64];
#pragma unroll
  for (int e = 0; e < 64; ++e) { re[e] = lds[l * 68 + e]; im[e] = 0.0f; }
  fft64<-1>(re, im);
  const int b = bi >> 8, i = bi & 255;
  const int j = jblk * 64 + l;
#pragma unroll
  for (int k = 0; k <= 32; ++k) {
    const size_t plane = (size_t)(b * 33 + k) * (256 * 512);
    Af[plane + (size_t)i * 512 + j]       = (__bf16)re[k];
    Af[plane + (size_t)i * 512 + 256 + j] = (__bf16)im[k];
  }
}

// ---------------- kernel 2: FFT of B -> Bn (compact, transposed) ----------------
__global__ __launch_bounds__(64) void fft_b_kernel(const float* __restrict__ B,
                                                   __bf16* __restrict__ Bn) {
  const int blk = blockIdx.x;
  const int jblk = blk & 3;
  const int bn = blk >> 2;                  // b*256 + n
  const int b = bn >> 8, n = bn & 255;
  const int l = threadIdx.x;
  const int lm16 = l & 15, lq4 = l >> 4;
  __shared__ float lds[64 * 68];
#pragma unroll
  for (int it = 0; it < 16; ++it) {
    const int r = it * 4 + lq4;             // j within block of 64
    const size_t base = (((size_t)b * 256 + (size_t)(jblk * 64 + r)) * 256 + n) * 64;
    const float4 v = *(const float4*)&B[base + lm16 * 4];
    *(float4*)&lds[r * 68 + lm16 * 4] = v;
  }
  __syncthreads();
  float re[64], im[64];
#pragma unroll
  for (int e = 0; e < 64; ++e) { re[e] = lds[l * 68 + e]; im[e] = 0.0f; }
  fft64<-1>(re, im);
  const int j = jblk * 64 + l;
#pragma unroll
  for (int k = 0; k <= 32; ++k) {
    const size_t plane = (size_t)(b * 33 + k) * (256 * 512);
    Bn[plane + (size_t)n * 512 + j]       = (__bf16)re[k];   // Br
    Bn[plane + (size_t)n * 512 + 256 + j] = (__bf16)im[k];   // Bi
  }
}

// ---------------- kernel 3: compact complex GEMM --------------------------------
// Per plane g: Cr = Ar*Br^T - Ai*Bi^T ; Ci = Ar*Bi^T + Ai*Br^T  (K=256)
// Block: 128(i) x 128(n) complex, 4 waves of 64x64. BK=32, XOR-swizzled LDS.
__device__ __forceinline__ void gload_lds16(const void* g, void* l) {
  __builtin_amdgcn_global_load_lds(
      (const __attribute__((address_space(1))) void*)g,
      (__attribute__((address_space(3))) void*)l, 16, 0, 0);
}

__device__ __forceinline__ bf16x8 neg8(bf16x8 v) {
  union { bf16x8 b; uint32_t u[4]; } x;
  x.b = v;
  x.u[0] ^= 0x80008000u; x.u[1] ^= 0x80008000u;
  x.u[2] ^= 0x80008000u; x.u[3] ^= 0x80008000u;
  return x.b;
}

__global__ __launch_bounds__(256, 2) void gemm_kernel(const __bf16* __restrict__ Af,
                                                      const __bf16* __restrict__ Bn,
                                                      __bf16* __restrict__ Cf) {
  // XCD-aware mapping: blocks bid%8==x land on XCD x; give each XCD 33 planes.
  const int bid = blockIdx.x;
  const int x = bid & 7, qx = bid >> 3;     // qx 0..131
  const int g = x * 33 + (qx >> 2);
  const int tile = qx & 3;
  const int i0 = (tile >> 1) * 128, n0 = (tile & 1) * 128;

  const int tid = threadIdx.x;
  const int lane = tid & 63, wv = tid >> 6;
  const int wm = wv >> 1, wn = wv & 1;
  const int lm = lane & 15, qq = lane >> 4;

  __shared__ __bf16 S[4][128 * 32];         // Asr, Asi, Bsr, Bsi (8 KB each)

  const __bf16* aPlane = Af + (size_t)g * (256 * 512);
  const __bf16* bPlane = Bn + (size_t)g * (256 * 512);

  // Staging: wave wv owns tile wv. 1024B chunk = 16 rows x (4 x 16B swizzled chunks).
  // LDS layout: elem offset(row, klog) = row*32 + ((kchunk ^ ((row>>1)&3))*8 + k%8
  const int row_in = lane >> 2;             // 0..15
  const int c_phys = lane & 3;
  const int c_log = c_phys ^ ((row_in >> 1) & 3);
  const __bf16* stageBase = (wv < 2 ? aPlane : bPlane);
  const int r0 = (wv < 2 ? i0 : n0);
  const int colOff = (wv & 1) * 256;        // real half / imag half
  const __bf16* gsrc0 = stageBase + (size_t)(r0 + row_in) * 512 + colOff + c_log * 8;
  char* ldst = (char*)&S[wv][0];

  f32x4 acc_r[4][4], acc_i[4][4];
#pragma unroll
  for (int mi = 0; mi < 4; ++mi)
#pragma unroll
    for (int ni = 0; ni < 4; ++ni) {
      acc_r[mi][ni] = f32x4{0.f, 0.f, 0.f, 0.f};
      acc_i[mi][ni] = f32x4{0.f, 0.f, 0.f, 0.f};
    }

  // Read-side swizzled offsets (elements): R*32 + ((qq ^ ((R>>1)&3))*8)
  int aoff[4], boff[4];
#pragma unroll
  for (int mi = 0; mi < 4; ++mi) {
    const int R = wm * 64 + mi * 16 + lm;
    aoff[mi] = R * 32 + ((qq ^ ((R >> 1) & 3)) * 8);
  }
#pragma unroll
  for (int ni = 0; ni < 4; ++ni) {
    const int R = wn * 64 + ni * 16 + lm;
    boff[ni] = R * 32 + ((qq ^ ((R >> 1) & 3)) * 8);
  }

  for (int kt = 0; kt < 8; ++kt) {
#pragma unroll
    for (int p = 0; p < 8; ++p) {
      gload_lds16(gsrc0 + (size_t)p * 16 * 512 + kt * 32, ldst + p * 1024);
    }
    __syncthreads();

    bf16x8 ar[4], ai[4], br[4], bi[4], nbi[4];
#pragma unroll
    for (int mi = 0; mi < 4; ++mi) {
      ar[mi] = *(const bf16x8*)&S[0][aoff[mi]];
      ai[mi] = *(const bf16x8*)&S[1][aoff[mi]];
    }
#pragma unroll
    for (int ni = 0; ni < 4; ++ni) {
      br[ni]  = *(const bf16x8*)&S[2][boff[ni]];
      bi[ni]  = *(const bf16x8*)&S[3][boff[ni]];
      nbi[ni] = neg8(bi[ni]);
    }
#pragma unroll
    for (int mi = 0; mi < 4; ++mi)
#pragma unroll
      for (int ni = 0; ni < 4; ++ni) {
        acc_r[mi][ni] = __builtin_amdgcn_mfma_f32_16x16x32_bf16(ar[mi], br[ni],  acc_r[mi][ni], 0, 0, 0);
        acc_r[mi][ni] = __builtin_amdgcn_mfma_f32_16x16x32_bf16(ai[mi], nbi[ni], acc_r[mi][ni], 0, 0, 0);
        acc_i[mi][ni] = __builtin_amdgcn_mfma_f32_16x16x32_bf16(ar[mi], bi[ni],  acc_i[mi][ni], 0, 0, 0);
        acc_i[mi][ni] = __builtin_amdgcn_mfma_f32_16x16x32_bf16(ai[mi], br[ni],  acc_i[mi][ni], 0, 0, 0);
      }
    __syncthreads();
  }

  // epilogue: C/D layout col = lane&15, row = (lane>>4)*4 + reg  [m89/m91]
  __bf16* cPlane = Cf + (size_t)g * (256 * 512);
#pragma unroll
  for (int mi = 0; mi < 4; ++mi)
#pragma unroll
    for (int ni = 0; ni < 4; ++ni) {
      const int col = n0 + wn * 64 + ni * 16 + lm;
#pragma unroll
      for (int r = 0; r < 4; ++r) {
        const int row = i0 + wm * 64 + mi * 16 + qq * 4 + r;
        cPlane[(size_t)row * 512 + col]       = (__bf16)acc_r[mi][ni][r];
        cPlane[(size_t)row * 512 + 256 + col] = (__bf16)acc_i[mi][ni][r];
      }
    }
}

// ---------------- kernel 4: inverse FFT -> real C -------------------------------
__global__ __launch_bounds__(64) void ifft_kernel(const __bf16* __restrict__ Cf,
                                                  float* __restrict__ C) {
  const int blk = blockIdx.x;
  const int nblk = blk & 3;
  const int bi = blk >> 2;                  // b*256 + i
  const int b = bi >> 8, i = bi & 255;
  const int l = threadIdx.x;
  const int lm16 = l & 15, lq4 = l >> 4;
  const int n = nblk * 64 + l;
  float re[64], im[64];
#pragma unroll
  for (int k = 0; k <= 32; ++k) {
    const size_t plane = (size_t)(b * 33 + k) * (256 * 512);
    const float cr = (float)Cf[plane + (size_t)i * 512 + n];
    const float ci = (float)Cf[plane + (size_t)i * 512 + 256 + n];
    re[k] = cr; im[k] = ci;
    if (k >= 1 && k <= 31) { re[64 - k] = cr; im[64 - k] = -ci; }
  }
  fft64<1>(re, im);
  __shared__ float lds[64 * 68];            // [n-within][t], stride 68
#pragma unroll
  for (int t = 0; t < 64; ++t) lds[l * 68 + t] = re[t] * (1.0f / 64.0f);
  __syncthreads();
  const size_t base = (((size_t)b * 256 + i) * 256 + (size_t)nblk * 64) * 64;
#pragma unroll
  for (int it = 0; it < 16; ++it) {
    const int r = it * 4 + lq4;             // n-within-block
    const float4 v = *(const float4*)&lds[r * 68 + lm16 * 4];
    *(float4*)&C[base + (size_t)r * 64 + lm16 * 4] = v;
  }
}

// ---------------- launcher -------------------------------------------------------
extern "C" void kernel_launch(void* const* d_in, const int* in_sizes, int n_in,
                              void* d_out, int out_size, void* d_ws, size_t ws_size,
                              hipStream_t stream) {
  const float* A = (const float*)d_in[0];
  const float* B = (const float*)d_in[1];
  float* C = (float*)d_out;

  char* ws = (char*)d_ws;
  const size_t planeBytes = (size_t)264 * 256 * 512 * 2;   // 69.2 MB each
  __bf16* Af = (__bf16*)ws;
  __bf16* Bn = (__bf16*)(ws + planeBytes);
  __bf16* Cf = (__bf16*)(ws + 2 * planeBytes);

  fft_a_kernel<<<8192, 64, 0, stream>>>(A, Af);
  fft_b_kernel<<<8192, 64, 0, stream>>>(B, Bn);
  gemm_kernel<<<1056, 256, 0, stream>>>(Af, Bn, Cf);
  ifft_kernel<<<8192, 64, 0, stream>>>(Cf, C);
}